// Round 2
// baseline (81.197 us; speedup 1.0000x reference)
//
#include <hip/hip_runtime.h>
#include <hip/hip_bf16.h>

#define BB 256
#define AA 512
#define DD 200
#define ADIM 600
#define NKC 5
#define KCH 120   // 600 / 5

// ws layout (floats): X1[256*600] at 0; parts[5][256*600] at 153600

__global__ __launch_bounds__(640) void k_mlp1(const float* __restrict__ obs,
                                              const float* __restrict__ W1,
                                              const float* __restrict__ b1,
                                              float* __restrict__ X1) {
  __shared__ float s_obs[4 * DD];
  const int bg = blockIdx.x;  // 64 groups of 4 batch rows
  const int tid = threadIdx.x;
  for (int idx = tid; idx < 4 * DD; idx += 640) {
    const int r = idx / DD, c = idx % DD;
    s_obs[idx] = obs[(bg * 4 + r) * DD + c];
  }
  __syncthreads();
  const int j = tid;
  if (j < ADIM) {
    const float bv = b1[j];
    float acc[4];
#pragma unroll
    for (int r = 0; r < 4; ++r) acc[r] = bv;
    for (int k = 0; k < DD; ++k) {
      const float w = W1[k * ADIM + j];
#pragma unroll
      for (int r = 0; r < 4; ++r) acc[r] = fmaf(s_obs[r * DD + k], w, acc[r]);
    }
#pragma unroll
    for (int r = 0; r < 4; ++r)
      X1[(bg * 4 + r) * ADIM + j] = fmaxf(acc[r], 0.0f);
  }
}

__global__ __launch_bounds__(640) void k_mlp2(const float* __restrict__ X1,
                                              const float* __restrict__ W2,
                                              float* __restrict__ parts) {
  __shared__ __align__(16) float s_x1[8 * KCH];
  const int bg = blockIdx.x / NKC;  // 32 groups of 8 batch rows
  const int kc = blockIdx.x % NKC;
  const int tid = threadIdx.x;
  for (int idx = tid; idx < 8 * KCH; idx += 640) {
    const int r = idx / KCH, c = idx % KCH;
    s_x1[idx] = X1[(bg * 8 + r) * ADIM + kc * KCH + c];
  }
  __syncthreads();
  const int j = tid;
  if (j < ADIM) {
    float acc[8];
#pragma unroll
    for (int r = 0; r < 8; ++r) acc[r] = 0.0f;
    for (int k4 = 0; k4 < KCH; k4 += 4) {
      const float w0 = W2[(kc * KCH + k4 + 0) * ADIM + j];
      const float w1 = W2[(kc * KCH + k4 + 1) * ADIM + j];
      const float w2 = W2[(kc * KCH + k4 + 2) * ADIM + j];
      const float w3 = W2[(kc * KCH + k4 + 3) * ADIM + j];
#pragma unroll
      for (int r = 0; r < 8; ++r) {
        const float4 xv = *reinterpret_cast<const float4*>(&s_x1[r * KCH + k4]);
        acc[r] = fmaf(xv.x, w0, fmaf(xv.y, w1, fmaf(xv.z, w2, fmaf(xv.w, w3, acc[r]))));
      }
    }
#pragma unroll
    for (int r = 0; r < 8; ++r)
      parts[kc * (BB * ADIM) + (bg * 8 + r) * ADIM + j] = acc[r];
  }
}

__device__ inline float waveMax(float v) {
#pragma unroll
  for (int o = 32; o > 0; o >>= 1) v = fmaxf(v, __shfl_xor(v, o));
  return v;
}
__device__ inline float waveSum(float v) {
#pragma unroll
  for (int o = 32; o > 0; o >>= 1) v += __shfl_xor(v, o);
  return v;
}

__global__ __launch_bounds__(512) void k_score(
    const float* __restrict__ parts, const float* __restrict__ b2,
    const float* __restrict__ rel, const float* __restrict__ entt,
    const float* __restrict__ trip, const int* __restrict__ r_sp,
    const int* __restrict__ e_sp, const int* __restrict__ t_id,
    const int* __restrict__ amask, float* __restrict__ out_dist,
    float* __restrict__ out_ent) {
  __shared__ __align__(16) float s_x2[ADIM];
  __shared__ float s_red[8];
  const int b = blockIdx.x;
  const int tid = threadIdx.x;

  // X2 row = b2 + sum of K-chunk partials, staged in LDS
  for (int k = tid; k < ADIM; k += 512) {
    float v = b2[k];
#pragma unroll
    for (int kc = 0; kc < NKC; ++kc) v += parts[kc * (BB * ADIM) + b * ADIM + k];
    s_x2[k] = v;
  }
  __syncthreads();

  const int a = tid;
  const int r = r_sp[b * AA + a];
  const int e = e_sp[b * AA + a];
  const int t = t_id[b * AA + a];
  const float mask = (float)amask[b * AA + a];

  const float4* pr = reinterpret_cast<const float4*>(rel + (size_t)r * DD);
  const float4* pe = reinterpret_cast<const float4*>(entt + (size_t)e * DD);
  const float4* pt = reinterpret_cast<const float4*>(trip + (size_t)t * DD);
  const float4* sx = reinterpret_cast<const float4*>(s_x2);

  float acc4[4] = {0.f, 0.f, 0.f, 0.f};
#pragma unroll 10
  for (int q = 0; q < 50; ++q) {
    const float4 v = pr[q];
    const float4 x = sx[q];
    acc4[q & 3] = fmaf(v.x, x.x, fmaf(v.y, x.y, fmaf(v.z, x.z, fmaf(v.w, x.w, acc4[q & 3]))));
  }
#pragma unroll 10
  for (int q = 0; q < 50; ++q) {
    const float4 v = pe[q];
    const float4 x = sx[50 + q];
    acc4[q & 3] = fmaf(v.x, x.x, fmaf(v.y, x.y, fmaf(v.z, x.z, fmaf(v.w, x.w, acc4[q & 3]))));
  }
#pragma unroll 10
  for (int q = 0; q < 50; ++q) {
    const float4 v = pt[q];
    const float4 x = sx[100 + q];
    acc4[q & 3] = fmaf(v.x, x.x, fmaf(v.y, x.y, fmaf(v.z, x.z, fmaf(v.w, x.w, acc4[q & 3]))));
  }
  const float score = (acc4[0] + acc4[1]) + (acc4[2] + acc4[3]);
  const float logit = score - (1.0f - mask) * 1e31f;

  // block max
  float m = waveMax(logit);
  if ((tid & 63) == 0) s_red[tid >> 6] = m;
  __syncthreads();
  float bm = s_red[0];
#pragma unroll
  for (int w = 1; w < 8; ++w) bm = fmaxf(bm, s_red[w]);
  __syncthreads();

  const float ev = __expf(logit - bm);
  float s = waveSum(ev);
  if ((tid & 63) == 0) s_red[tid >> 6] = s;
  __syncthreads();
  float bs = 0.0f;
#pragma unroll
  for (int w = 0; w < 8; ++w) bs += s_red[w];

  const float p = ev / bs;
  out_dist[b * AA + a] = p;

  const float term = -p * __logf(p + 2.220446049250313e-16f);
  __syncthreads();
  float es = waveSum(term);
  if ((tid & 63) == 0) s_red[tid >> 6] = es;
  __syncthreads();
  if (tid == 0) {
    float etot = 0.0f;
#pragma unroll
    for (int w = 0; w < 8; ++w) etot += s_red[w];
    out_ent[b] = etot;
  }
}

extern "C" void kernel_launch(void* const* d_in, const int* in_sizes, int n_in,
                              void* d_out, int out_size, void* d_ws, size_t ws_size,
                              hipStream_t stream) {
  const float* obs  = (const float*)d_in[0];
  const float* W1   = (const float*)d_in[1];
  const float* b1   = (const float*)d_in[2];
  const float* W2   = (const float*)d_in[3];
  const float* b2   = (const float*)d_in[4];
  const float* rel  = (const float*)d_in[5];
  const float* entt = (const float*)d_in[6];
  const float* trip = (const float*)d_in[7];
  const int* r_sp   = (const int*)d_in[8];
  const int* e_sp   = (const int*)d_in[9];
  const int* t_id   = (const int*)d_in[10];
  const int* amask  = (const int*)d_in[11];

  float* ws = (float*)d_ws;
  float* X1 = ws;                   // 153600 floats
  float* parts = ws + BB * ADIM;    // 5 * 153600 floats

  float* out = (float*)d_out;

  k_mlp1<<<64, 640, 0, stream>>>(obs, W1, b1, X1);
  k_mlp2<<<32 * NKC, 640, 0, stream>>>(X1, W2, parts);
  k_score<<<BB, 512, 0, stream>>>(parts, b2, rel, entt, trip, r_sp, e_sp, t_id,
                                  amask, out, out + BB * AA);
}

// Round 3
// 76.560 us; speedup vs baseline: 1.0606x; 1.0606x over previous
//
#include <hip/hip_runtime.h>
#include <hip/hip_bf16.h>

#define BB 256
#define AA 512
#define DD 200
#define ADIM 600
#define NKC 5
#define KCH 120   // 600 / 5

// ws layout (floats):
//   X1     at 0        (256*600 = 153600)
//   parts  at 153600   (5*256*600 = 768000)
//   logits at 921600   (256*512 = 131072)

__global__ __launch_bounds__(640) void k_mlp1(const float* __restrict__ obs,
                                              const float* __restrict__ W1,
                                              const float* __restrict__ b1,
                                              float* __restrict__ X1) {
  __shared__ float s_obs[4 * DD];
  const int bg = blockIdx.x;  // 64 groups of 4 batch rows
  const int tid = threadIdx.x;
  for (int idx = tid; idx < 4 * DD; idx += 640) {
    const int r = idx / DD, c = idx % DD;
    s_obs[idx] = obs[(bg * 4 + r) * DD + c];
  }
  __syncthreads();
  const int j = tid;
  if (j < ADIM) {
    const float bv = b1[j];
    float acc[4];
#pragma unroll
    for (int r = 0; r < 4; ++r) acc[r] = bv;
    for (int k = 0; k < DD; ++k) {
      const float w = W1[k * ADIM + j];
#pragma unroll
      for (int r = 0; r < 4; ++r) acc[r] = fmaf(s_obs[r * DD + k], w, acc[r]);
    }
#pragma unroll
    for (int r = 0; r < 4; ++r)
      X1[(bg * 4 + r) * ADIM + j] = fmaxf(acc[r], 0.0f);
  }
}

__global__ __launch_bounds__(640) void k_mlp2(const float* __restrict__ X1,
                                              const float* __restrict__ W2,
                                              float* __restrict__ parts) {
  __shared__ __align__(16) float s_x1[8 * KCH];
  const int bg = blockIdx.x / NKC;  // 32 groups of 8 batch rows
  const int kc = blockIdx.x % NKC;
  const int tid = threadIdx.x;
  for (int idx = tid; idx < 8 * KCH; idx += 640) {
    const int r = idx / KCH, c = idx % KCH;
    s_x1[idx] = X1[(bg * 8 + r) * ADIM + kc * KCH + c];
  }
  __syncthreads();
  const int j = tid;
  if (j < ADIM) {
    float acc[8];
#pragma unroll
    for (int r = 0; r < 8; ++r) acc[r] = 0.0f;
    for (int k4 = 0; k4 < KCH; k4 += 4) {
      const float w0 = W2[(kc * KCH + k4 + 0) * ADIM + j];
      const float w1 = W2[(kc * KCH + k4 + 1) * ADIM + j];
      const float w2 = W2[(kc * KCH + k4 + 2) * ADIM + j];
      const float w3 = W2[(kc * KCH + k4 + 3) * ADIM + j];
#pragma unroll
      for (int r = 0; r < 8; ++r) {
        const float4 xv = *reinterpret_cast<const float4*>(&s_x1[r * KCH + k4]);
        acc[r] = fmaf(xv.x, w0, fmaf(xv.y, w1, fmaf(xv.z, w2, fmaf(xv.w, w3, acc[r]))));
      }
    }
#pragma unroll
    for (int r = 0; r < 8; ++r)
      parts[kc * (BB * ADIM) + (bg * 8 + r) * ADIM + j] = acc[r];
  }
}

// 4 threads per action; sub-thread s handles float4 indices q = s, s+4, ... of
// each 50-float4 table segment. Lanes 4i..4i+3 read contiguous 64B of one row.
__global__ __launch_bounds__(512, 4) void k_logits(
    const float* __restrict__ parts, const float* __restrict__ b2,
    const float* __restrict__ rel, const float* __restrict__ entt,
    const float* __restrict__ trip, const int* __restrict__ r_sp,
    const int* __restrict__ e_sp, const int* __restrict__ t_id,
    const int* __restrict__ amask, float* __restrict__ logits) {
  __shared__ __align__(16) float s_x2[ADIM];
  const int b = blockIdx.x >> 2;
  const int ch = blockIdx.x & 3;
  const int tid = threadIdx.x;

  for (int k = tid; k < ADIM; k += 512) {
    float v = b2[k];
#pragma unroll
    for (int kc = 0; kc < NKC; ++kc) v += parts[kc * (BB * ADIM) + b * ADIM + k];
    s_x2[k] = v;
  }
  __syncthreads();

  const int a = ch * 128 + (tid >> 2);
  const int sub = tid & 3;
  const int r = r_sp[b * AA + a];
  const int e = e_sp[b * AA + a];
  const int t = t_id[b * AA + a];
  const float mask = (float)amask[b * AA + a];

  const float4* pr = reinterpret_cast<const float4*>(rel + (size_t)r * DD);
  const float4* pe = reinterpret_cast<const float4*>(entt + (size_t)e * DD);
  const float4* pt = reinterpret_cast<const float4*>(trip + (size_t)t * DD);
  const float4* sx = reinterpret_cast<const float4*>(s_x2);

  float a0 = 0.f, a1 = 0.f, a2 = 0.f;
#pragma unroll
  for (int i = 0; i < 13; ++i) {
    const int q = sub + (i << 2);
    if (q < 50) {
      const float4 vr = pr[q];
      const float4 xr = sx[q];
      a0 = fmaf(vr.x, xr.x, fmaf(vr.y, xr.y, fmaf(vr.z, xr.z, fmaf(vr.w, xr.w, a0))));
      const float4 ve = pe[q];
      const float4 xe = sx[50 + q];
      a1 = fmaf(ve.x, xe.x, fmaf(ve.y, xe.y, fmaf(ve.z, xe.z, fmaf(ve.w, xe.w, a1))));
      const float4 vt = pt[q];
      const float4 xt = sx[100 + q];
      a2 = fmaf(vt.x, xt.x, fmaf(vt.y, xt.y, fmaf(vt.z, xt.z, fmaf(vt.w, xt.w, a2))));
    }
  }
  float s = (a0 + a1) + a2;
  s += __shfl_xor(s, 1);
  s += __shfl_xor(s, 2);
  if (sub == 0) {
    logits[b * AA + a] = s - (1.0f - mask) * 1e31f;
  }
}

__device__ inline float waveMax(float v) {
#pragma unroll
  for (int o = 32; o > 0; o >>= 1) v = fmaxf(v, __shfl_xor(v, o));
  return v;
}
__device__ inline float waveSum(float v) {
#pragma unroll
  for (int o = 32; o > 0; o >>= 1) v += __shfl_xor(v, o);
  return v;
}

__global__ __launch_bounds__(512) void k_soft(const float* __restrict__ logits,
                                              float* __restrict__ out_dist,
                                              float* __restrict__ out_ent) {
  __shared__ float s_red[8];
  const int b = blockIdx.x;
  const int tid = threadIdx.x;
  const float logit = logits[b * AA + tid];

  float m = waveMax(logit);
  if ((tid & 63) == 0) s_red[tid >> 6] = m;
  __syncthreads();
  float bm = s_red[0];
#pragma unroll
  for (int w = 1; w < 8; ++w) bm = fmaxf(bm, s_red[w]);
  __syncthreads();

  const float ev = __expf(logit - bm);
  float s = waveSum(ev);
  if ((tid & 63) == 0) s_red[tid >> 6] = s;
  __syncthreads();
  float bs = 0.0f;
#pragma unroll
  for (int w = 0; w < 8; ++w) bs += s_red[w];

  const float p = ev / bs;
  out_dist[b * AA + tid] = p;

  const float term = -p * __logf(p + 2.220446049250313e-16f);
  __syncthreads();
  float es = waveSum(term);
  if ((tid & 63) == 0) s_red[tid >> 6] = es;
  __syncthreads();
  if (tid == 0) {
    float etot = 0.0f;
#pragma unroll
    for (int w = 0; w < 8; ++w) etot += s_red[w];
    out_ent[b] = etot;
  }
}

extern "C" void kernel_launch(void* const* d_in, const int* in_sizes, int n_in,
                              void* d_out, int out_size, void* d_ws, size_t ws_size,
                              hipStream_t stream) {
  const float* obs  = (const float*)d_in[0];
  const float* W1   = (const float*)d_in[1];
  const float* b1   = (const float*)d_in[2];
  const float* W2   = (const float*)d_in[3];
  const float* b2   = (const float*)d_in[4];
  const float* rel  = (const float*)d_in[5];
  const float* entt = (const float*)d_in[6];
  const float* trip = (const float*)d_in[7];
  const int* r_sp   = (const int*)d_in[8];
  const int* e_sp   = (const int*)d_in[9];
  const int* t_id   = (const int*)d_in[10];
  const int* amask  = (const int*)d_in[11];

  float* ws = (float*)d_ws;
  float* X1     = ws;                         // 153600 floats
  float* parts  = ws + BB * ADIM;             // 768000 floats
  float* logits = ws + BB * ADIM * (1 + NKC); // 131072 floats

  float* out = (float*)d_out;

  k_mlp1<<<64, 640, 0, stream>>>(obs, W1, b1, X1);
  k_mlp2<<<32 * NKC, 640, 0, stream>>>(X1, W2, parts);
  k_logits<<<BB * 4, 512, 0, stream>>>(parts, b2, rel, entt, trip, r_sp, e_sp,
                                       t_id, amask, logits);
  k_soft<<<BB, 512, 0, stream>>>(logits, out, out + BB * AA);
}